// Round 11
// baseline (10608.669 us; speedup 1.0000x reference)
//
#include <hip/hip_runtime.h>

typedef unsigned short u16;
typedef unsigned int   u32;
typedef unsigned long long u64;

#define LTC_B 32
#define LTC_L 1024
#define LTC_D 512
#define LTC_H 512
#define NG 8               // groups
#define NP 16              // producer WGs per group (each owns 32+32 W rows)
#define NBG 4              // batches per group

typedef _Float16 f16x8  __attribute__((ext_vector_type(8)));
typedef _Float16 f16x2t __attribute__((ext_vector_type(2)));
typedef float    f32x4  __attribute__((ext_vector_type(4)));

static __device__ __forceinline__ u32 packh(float a, float b) {
    f16x2t p; p[0] = (_Float16)a; p[1] = (_Float16)b;
    return __builtin_bit_cast(u32, p);
}
static __device__ __forceinline__ float unplo(u32 w) {
    return (float)__builtin_bit_cast(f16x2t, w)[0];
}
static __device__ __forceinline__ float unphi(u32 w) {
    return (float)__builtin_bit_cast(f16x2t, w)[1];
}
static __device__ __forceinline__ float sigm(float x) {
    return 1.f / (1.f + __expf(-x));
}
static __device__ __forceinline__ float tanh_f(float x) {
    float e = __expf(2.f * x);          // inf-safe: e=inf -> 1, e=0 -> -1
    return 1.f - 2.f / (e + 1.f);
}
static __device__ __forceinline__ f16x8 cvt8(const float* p) {
    const float4 a = *(const float4*)p;
    const float4 b = *(const float4*)(p + 4);
    f16x8 r;
    r[0] = (_Float16)a.x; r[1] = (_Float16)a.y; r[2] = (_Float16)a.z; r[3] = (_Float16)a.w;
    r[4] = (_Float16)b.x; r[5] = (_Float16)b.y; r[6] = (_Float16)b.z; r[7] = (_Float16)b.w;
    return r;
}
static __device__ __forceinline__ bool stamp4(u64 a, u64 b, u64 c, u64 d, u32 k) {
    return ((u32)(a >> 32) == k) & ((u32)(b >> 32) == k) &
           ((u32)(c >> 32) == k) & ((u32)(d >> 32) == k);
}

// ---------------------------------------------------------------------------
// C[M,512](f16) = A[M,512](f32) . W[:,:512]^T(f32, row stride ldb) + bias(f32)
// ---------------------------------------------------------------------------
__global__ __launch_bounds__(256) void gemm_a32_c16(
    const float* __restrict__ A, const float* __restrict__ W, int ldb,
    const float* __restrict__ bias, u16* __restrict__ C)
{
    const int wave = threadIdx.x >> 6;
    const int lane = threadIdx.x & 63;
    const int tile = blockIdx.x * 4 + wave;
    const int nt = tile & 7;
    const int mt = tile >> 3;
    const int r16 = lane & 15;
    const int kq  = (lane >> 4) * 8;

    const float* ap = A + (size_t)(mt * 64 + r16) * LTC_D + kq;
    const float* wp = W + (size_t)(nt * 64 + r16) * ldb + kq;

    f32x4 acc[4][4];
    #pragma unroll
    for (int i = 0; i < 4; ++i)
        #pragma unroll
        for (int jj = 0; jj < 4; ++jj) acc[i][jj] = (f32x4){0.f, 0.f, 0.f, 0.f};

    for (int ks = 0; ks < 16; ++ks) {
        f16x8 af[4], bf[4];
        #pragma unroll
        for (int t = 0; t < 4; ++t) {
            af[t] = cvt8(ap + (size_t)t * 16 * LTC_D + ks * 32);
            bf[t] = cvt8(wp + (size_t)t * 16 * ldb  + ks * 32);
        }
        #pragma unroll
        for (int mi = 0; mi < 4; ++mi)
            #pragma unroll
            for (int ni = 0; ni < 4; ++ni)
                acc[mi][ni] = __builtin_amdgcn_mfma_f32_16x16x32_f16(
                    af[mi], bf[ni], acc[mi][ni], 0, 0, 0);
    }
    const int row = (lane >> 4) * 4;   // C/D: col=lane&15 (n), row=(lane>>4)*4+reg (m)
    const int col = lane & 15;
    #pragma unroll
    for (int ni = 0; ni < 4; ++ni) {
        const int n = nt * 64 + ni * 16 + col;
        const float bv = bias[n];
        #pragma unroll
        for (int mi = 0; mi < 4; ++mi)
            #pragma unroll
            for (int r = 0; r < 4; ++r) {
                _Float16 h = (_Float16)(acc[mi][ni][r] + bv);
                C[(size_t)(mt * 64 + mi * 16 + row + r) * LTC_H + n] =
                    __builtin_bit_cast(u16, h);
            }
    }
}

// ---------------------------------------------------------------------------
// C[M,512](f32) = A[M,512](f16) . W^T(f32, row stride 512) + bias(f32)
// ---------------------------------------------------------------------------
__global__ __launch_bounds__(256) void gemm_a16_c32(
    const u16* __restrict__ A, const float* __restrict__ W,
    const float* __restrict__ bias, float* __restrict__ C)
{
    const int wave = threadIdx.x >> 6;
    const int lane = threadIdx.x & 63;
    const int tile = blockIdx.x * 4 + wave;
    const int nt = tile & 7;
    const int mt = tile >> 3;
    const int r16 = lane & 15;
    const int kq  = (lane >> 4) * 8;

    const _Float16* ap = (const _Float16*)A + (size_t)(mt * 64 + r16) * LTC_D + kq;
    const float*    wp = W + (size_t)(nt * 64 + r16) * LTC_H + kq;

    f32x4 acc[4][4];
    #pragma unroll
    for (int i = 0; i < 4; ++i)
        #pragma unroll
        for (int jj = 0; jj < 4; ++jj) acc[i][jj] = (f32x4){0.f, 0.f, 0.f, 0.f};

    for (int ks = 0; ks < 16; ++ks) {
        f16x8 af[4], bf[4];
        #pragma unroll
        for (int t = 0; t < 4; ++t) {
            af[t] = *(const f16x8*)(ap + (size_t)t * 16 * LTC_D + ks * 32);
            bf[t] = cvt8(wp + (size_t)t * 16 * LTC_H + ks * 32);
        }
        #pragma unroll
        for (int mi = 0; mi < 4; ++mi)
            #pragma unroll
            for (int ni = 0; ni < 4; ++ni)
                acc[mi][ni] = __builtin_amdgcn_mfma_f32_16x16x32_f16(
                    af[mi], bf[ni], acc[mi][ni], 0, 0, 0);
    }
    const int row = (lane >> 4) * 4;
    const int col = lane & 15;
    #pragma unroll
    for (int ni = 0; ni < 4; ++ni) {
        const int n = nt * 64 + ni * 16 + col;
        const float bv = bias[n];
        #pragma unroll
        for (int mi = 0; mi < 4; ++mi)
            #pragma unroll
            for (int r = 0; r < 4; ++r)
                C[(size_t)(mt * 64 + mi * 16 + row + r) * LTC_H + n] =
                    acc[mi][ni][r] + bv;
    }
}

// ---------------------------------------------------------------------------
// ODE scan: 8 groups x 4 batches, 16 producer WGs per group (128 WGs of
// 320 threads). FUSED SINGLE-STREAM 3-PHASE with wave specialization.
// Round 9 proved specialization (+12%); its counters showed the residual is
// the poll leg (~1300 cyc) paid TWICE (X and Y streams) plus the matvec
// paid twice. With legs on separate waves the 2-stream offset is no longer
// needed for overlap — fuse the streams and pay each leg ONCE:
//   P1: waves 0-3 matvec over hTu rows 0-3 (all 4 batches @ stamp k) -> red
//       (one pass: LDS read traffic and MFMA count halve vs round 9)
//   P2: wave 4 (64 updaters) update all 4 batches, publish stamp k+1
//       (publish early-in-phase, round-8 lesson) + own-col LDS write
//   P3: waves 0-3 poll all 4 rows (col tid, 4 loads, skip own 16 cols)
//       -> hTu. Updaters idle: their publish-store acks drain under P3 and
//       never sit in front of a poll (round-5 lesson: every load is issued
//       AND consumed within one barrier interval; vmcnt is in-order).
// No intra-phase races remain (each phase has exclusive hTu/red access).
// Exchange channel = the VALIDATED one, bytes unchanged: stamped u64
// (stamp<<32 | f16 pair), relaxed agent-scope atomics, bounded spin budget
// (protocol failure => wrong answer via absmax, never a hang). Overwrite/
// parity safety, same transitive argument: publishing k+2 (parity k&1)
// requires this WG's P3-check of k+1 passed, which requires every peer
// published k+1, which requires each peer's P3-read of k completed.
// Prologue publishes stamp-0 zeros; stale prior-run stamps are rejected.
// ---------------------------------------------------------------------------
__global__ __launch_bounds__(320) void ltc_scan(
    u32* __restrict__ drive,            // f16 pairs; rewritten with fwd
    const u32* __restrict__ gatex,      // f16 pairs
    const float* __restrict__ W_rec,
    const float* __restrict__ W_gate,
    const float* __restrict__ log_tau,
    u64* __restrict__ hbuf,             // [2 par][8 g][4 b][256] stamped pairs
    float* __restrict__ hlast)
{
    const int g   = blockIdx.x & 7;     // group
    const int p   = blockIdx.x >> 3;    // producer slice 0..15
    const int tid = threadIdx.x;
    const int lane = tid & 63;
    const int wv   = tid >> 6;          // 0-3 matvec+poll, 4 update/publish

    __shared__ u32 hTu[16][260];        // h pairs; rows 0-3 = batches, 4-15 zero
    __shared__ float red[64][17];       // matvec results [n][m]

    const int kq = (lane >> 4) * 8;

    // ---- matvec waves: B-fragments (32 W_rec + 32 Wg_h rows) in registers
    f16x8 Wf[16];
    if (wv < 4) {
        const int nl = wv * 16 + (lane & 15);      // 0..63
        const float* wrow = (nl < 32)
            ? (W_rec  + (size_t)(32 * p + nl) * LTC_H)
            : (W_gate + (size_t)(32 * p + nl - 32) * (LTC_D + LTC_H) + LTC_D);
        #pragma unroll
        for (int ks = 0; ks < 16; ++ks) Wf[ks] = cvt8(wrow + ks * 32 + kq);
    }

    for (int i = tid; i < 16 * 260; i += 320) (&hTu[0][0])[i] = 0;  // h0 = 0

    // ---- updater setup: wave 4 -> ut 0..63, 4 batches x 16 pairs
    const int ut = tid - 256;
    const bool isupd = (ut >= 0);       // wave 4 exactly (tid 256..319)
    const int ub = ut >> 4;             // batch 0..3
    const int jp = ut & 15;
    const int j0 = 32 * p + 2 * jp;
    const int gb = g * NBG + ub;        // global batch
    float h0 = 0.f, h1 = 0.f, stau0 = 0.f, stau1 = 0.f;
    size_t dwofs = 0;
    if (isupd) {
        stau0 = (1.f / 6.f) * __expf(-log_tau[j0]);
        stau1 = (1.f / 6.f) * __expf(-log_tau[j0 + 1]);
        dwofs = (size_t)gb * LTC_L * 256 + 16 * p + jp;
        // prologue: publish initial h=0 with stamp 0 into parity 0
        __hip_atomic_store(hbuf + (size_t)g * (NBG * 256) + (size_t)ub * 256
                               + 16 * p + jp,
                           0ull, __ATOMIC_RELAXED, __HIP_MEMORY_SCOPE_AGENT);
    }
    __syncthreads();

    const _Float16* hrow = (const _Float16*)&hTu[lane & 15][0];
    const int redn = wv * 16 + (lane & 15);    // valid for wv<4
    const int redb = (lane >> 4) * 4;
    u32 kp1 = 0;                        // stamp of current (gathered) state
    int budget = 1 << 22;               // per-thread failing-poll budget
    const bool pskip = ((tid >> 4) == p);  // poller's column is own (LDS shortcut)

    // prime l=0 inputs (updaters only)
    u32 dw = 0, gw = 0;
    if (isupd) { dw = drive[dwofs]; gw = gatex[dwofs]; }

    for (int l = 0; l < LTC_L; ++l) {
        const float d0 = unplo(dw), d1 = unphi(dw);
        const float gx0 = unplo(gw), gx1 = unphi(gw);
        // prefetch next step's inputs (updaters; drains at P1-end under mv)
        u32 dn = 0, gn = 0;
        if (isupd && l + 1 < LTC_L) {
            dn = drive[dwofs + (size_t)(l + 1) * 256];
            gn = gatex[dwofs + (size_t)(l + 1) * 256];
        }
        #pragma unroll 1
        for (int s = 0; s < 6; ++s) {
            const u32 knew = kp1 + 1;
            const size_t pbNew = (size_t)((knew & 1u) * NG + g) * (NBG * 256);

            // ============ P1: matvec (all 4 batches @ stamp kp1) ============
            if (wv < 4) {
                f32x4 acc0 = (f32x4){0.f, 0.f, 0.f, 0.f}, acc1 = acc0;
                #pragma unroll
                for (int ks = 0; ks < 16; ks += 2) {
                    const f16x8 a0 = *(const f16x8*)(hrow + ks * 32 + kq);
                    const f16x8 a1 = *(const f16x8*)(hrow + (ks + 1) * 32 + kq);
                    acc0 = __builtin_amdgcn_mfma_f32_16x16x32_f16(a0, Wf[ks],     acc0, 0, 0, 0);
                    acc1 = __builtin_amdgcn_mfma_f32_16x16x32_f16(a1, Wf[ks + 1], acc1, 0, 0, 0);
                }
                #pragma unroll
                for (int r = 0; r < 4; ++r) red[redn][redb + r] = acc0[r] + acc1[r];
            }
            __syncthreads();

            // ============ P2: update + publish (early) ============
            if (isupd) {
                const float rec0 = red[2 * jp][ub],     gh0 = red[32 + 2 * jp][ub];
                const float rec1 = red[2 * jp + 1][ub], gh1 = red[32 + 2 * jp + 1][ub];
                h0 += stau0 * (sigm(gx0 + gh0) * tanh_f(d0 + rec0) - h0);
                h1 += stau1 * (sigm(gx1 + gh1) * tanh_f(d1 + rec1) - h1);
                const u32 pr = packh(h0, h1);
                __hip_atomic_store(hbuf + pbNew + (size_t)ub * 256 + 16 * p + jp,
                                   ((u64)knew << 32) | (u64)pr,
                                   __ATOMIC_RELAXED, __HIP_MEMORY_SCOPE_AGENT);
                hTu[ub][16 * p + jp] = pr;          // own-col LDS shortcut
            }
            __syncthreads();

            // ============ P3: poll all 4 rows (waves 0-3) ============
            if (wv < 4 && !pskip) {
                const u64* b0 = hbuf + pbNew + tid;
                u64 a0 = __hip_atomic_load(b0,       __ATOMIC_RELAXED,
                                           __HIP_MEMORY_SCOPE_AGENT);
                u64 a1 = __hip_atomic_load(b0 + 256, __ATOMIC_RELAXED,
                                           __HIP_MEMORY_SCOPE_AGENT);
                u64 a2 = __hip_atomic_load(b0 + 512, __ATOMIC_RELAXED,
                                           __HIP_MEMORY_SCOPE_AGENT);
                u64 a3 = __hip_atomic_load(b0 + 768, __ATOMIC_RELAXED,
                                           __HIP_MEMORY_SCOPE_AGENT);
                while (!stamp4(a0, a1, a2, a3, knew) && --budget > 0) {
                    a0 = __hip_atomic_load(b0,       __ATOMIC_RELAXED,
                                           __HIP_MEMORY_SCOPE_AGENT);
                    a1 = __hip_atomic_load(b0 + 256, __ATOMIC_RELAXED,
                                           __HIP_MEMORY_SCOPE_AGENT);
                    a2 = __hip_atomic_load(b0 + 512, __ATOMIC_RELAXED,
                                           __HIP_MEMORY_SCOPE_AGENT);
                    a3 = __hip_atomic_load(b0 + 768, __ATOMIC_RELAXED,
                                           __HIP_MEMORY_SCOPE_AGENT);
                }
                hTu[0][tid] = (u32)a0;
                hTu[1][tid] = (u32)a1;
                hTu[2][tid] = (u32)a2;
                hTu[3][tid] = (u32)a3;
            }
            __syncthreads();
            kp1 = knew;
        }
        if (isupd) drive[dwofs + (size_t)l * 256] = packh(h0, h1);  // fwd
        dw = dn; gw = gn;
    }
    if (isupd) {
        hlast[(size_t)gb * LTC_H + j0]     = h0;
        hlast[(size_t)gb * LTC_H + j0 + 1] = h1;
    }
}

// ---------------------------------------------------------------------------
extern "C" void kernel_launch(void* const* d_in, const int* in_sizes, int n_in,
                              void* d_out, int out_size, void* d_ws, size_t ws_size,
                              hipStream_t stream)
{
    const float* x       = (const float*)d_in[0];
    const float* log_tau = (const float*)d_in[1];
    const float* W_in    = (const float*)d_in[2];
    const float* b_in    = (const float*)d_in[3];
    const float* W_rec   = (const float*)d_in[4];
    const float* W_gate  = (const float*)d_in[5];
    const float* b_gate  = (const float*)d_in[6];
    const float* W_out   = (const float*)d_in[7];
    const float* b_out   = (const float*)d_in[8];

    float* out   = (float*)d_out;                       // (32,1024,512) fp32
    float* hlast = out + (size_t)LTC_B * LTC_L * LTC_H; // (32,512) fp32

    u32* ws    = (u32*)d_ws;                   // 64 MB + 128 KB used
    u32* drive = ws;                           // 8388608 u32 (f16 pairs)
    u32* gatex = ws + 8388608;                 // 8388608 u32
    u64* hbuf  = (u64*)(ws + 16777216);        // 16384 u64 stamped pairs

    const int blocks = (LTC_B * LTC_L / 64) * (LTC_H / 64) / 4;   // 1024

    gemm_a32_c16<<<blocks, 256, 0, stream>>>(x, W_in, LTC_D, b_in, (u16*)drive);
    gemm_a32_c16<<<blocks, 256, 0, stream>>>(x, W_gate, LTC_D + LTC_H, b_gate, (u16*)gatex);
    ltc_scan<<<NG * NP, 320, 0, stream>>>(drive, gatex, W_rec, W_gate, log_tau,
                                          hbuf, hlast);
    gemm_a16_c32<<<blocks, 256, 0, stream>>>((const u16*)drive, W_out, b_out, out);
}